// Round 6
// baseline (839.567 us; speedup 1.0000x reference)
//
#include <hip/hip_runtime.h>

#define HID 50
#define NMID 7
#define LROWU 152   // ushorts per LDS h-row: 304 B, 16B-aligned, odd dword stride (76)

// ---- packed-parameter workspace (ushorts) ----
// Mid [L][t][s=0..6][64 lanes][8] ; In [t][64][8] ; Out [s=0..6][64][8]
#define MID_ELEMS (NMID * 4 * 7 * 64 * 8)
#define IN_ELEMS  (4 * 64 * 8)
#define OUT_ELEMS (7 * 64 * 8)
#define W_USHORTS (MID_ELEMS + IN_ELEMS + OUT_ELEMS)
#define BIAS_FLOATS (64 + NMID * 64 + 64)
#define PACK_THREADS (W_USHORTS + BIAS_FLOATS)

using short8 = __attribute__((ext_vector_type(8))) short;  // 8 bf16 (4 VGPRs)
using f32x4  = __attribute__((ext_vector_type(4))) float;  // MFMA C/D

__device__ __forceinline__ unsigned short bf16_rne(float f) {
    unsigned int u = __builtin_bit_cast(unsigned int, f);
    unsigned int r = (u + 0x7FFFu + ((u >> 16) & 1u)) >> 16;
    return (unsigned short)r;
}
__device__ __forceinline__ float bf16_f(unsigned short b) {
    unsigned int u = ((unsigned int)b) << 16;
    return __builtin_bit_cast(float, u);
}
__device__ __forceinline__ unsigned short bf16_lo(float w) {
    return bf16_rne(w - bf16_f(bf16_rne(w)));
}
__device__ __forceinline__ float tanh_fast(float v) {
    float e = __builtin_amdgcn_exp2f(v * 2.885390081777927f);
    return 1.0f - 2.0f * __builtin_amdgcn_rcpf(e + 1.0f);
}
// tanh -> truncating hi/lo split -> packed dword {lo_bf16 : hi_bf16}.
// hi = trunc16(v) (1 AND); lo = v - hi_f exact (Sterbenz); residual <= 2^-16|v|.
__device__ __forceinline__ unsigned int tanh_split_pack(float a) {
    float v = tanh_fast(a);
    unsigned int uv  = __builtin_bit_cast(unsigned int, v);
    unsigned int hif = uv & 0xFFFF0000u;
    float lo = v - __builtin_bit_cast(float, hif);
    unsigned int ul = __builtin_bit_cast(unsigned int, lo);
    return (ul & 0xFFFF0000u) | (uv >> 16);   // ushort0=hi, ushort1=lo
}

// LDS h-row (per point): interleaved [h0.hi,h0.lo, h1.hi,h1.lo, ...] 100 ushorts.
// A-chunks (8 ushorts = 4 (hi,lo) pairs) for chunk id c = s*4+quad:
//   c<13  : offset c*8      -> slots: j even = hi[e] pair Whi[e]; j odd = lo[e] pair Whi[e]
//   13..25: offset (c-13)*8 -> slots: j even = hi[e] pair Wlo[e]; j odd = 0
//   26,27 : offset 0, B=0
// where e = base*4 + j/2; e>=50 -> B=0. Covers hi*Whi + lo*Whi + hi*Wlo = 150 products.
__device__ __forceinline__ unsigned short pack_slot(const float* __restrict__ W, int ld,
                                                    int c, int j, int nn) {
    if (c >= 26) return 0;
    const bool first = (c < 13);
    int e = (first ? c : c - 13) * 4 + (j >> 1);
    if (e >= HID) return 0;
    float w = W[e * ld + nn];
    if ((j & 1) == 0) return first ? bf16_rne(w) : bf16_lo(w);  // hi slot
    return first ? bf16_rne(w) : (unsigned short)0;             // lo slot
}

__global__ void pack_params(const float* __restrict__ W_in, const float* __restrict__ b_in,
                            const float* __restrict__ W_mid, const float* __restrict__ b_mid,
                            const float* __restrict__ W_out, const float* __restrict__ b_out,
                            unsigned short* __restrict__ wp, float* __restrict__ bp) {
    int e = blockIdx.x * 256 + threadIdx.x;
    if (e < MID_ELEMS) {
        int L = e / 14336, r1 = e % 14336;
        int t = r1 / 3584,  r2 = r1 % 3584;
        int s = r2 / 512,   r3 = r2 % 512;
        int l = r3 / 8,     j  = r3 % 8;
        int c  = s * 4 + (l >> 4);
        int nn = t * 16 + (l & 15);
        wp[e] = (nn < HID) ? pack_slot(W_mid + L * HID * HID, HID, c, j, nn) : (unsigned short)0;
    } else if (e < MID_ELEMS + IN_ELEMS) {
        int e2 = e - MID_ELEMS;
        int t = e2 / 512, r = e2 % 512, l = r / 8, j = r % 8;
        int k  = (l >> 4) * 8 + j;          // single K=32 step, register A-frag
        int nn = t * 16 + (l & 15);
        unsigned short bits = 0;
        if (nn < HID) {
            // A slots: quad0 = [xh,yh,zh, xl,yl,zl, xh,yh], quad1 j0 = zh
            if (k < 3)      bits = bf16_rne(W_in[k * HID + nn]);        // hi*Whi
            else if (k < 6) bits = bf16_rne(W_in[(k - 3) * HID + nn]);  // lo*Whi
            else if (k < 9) bits = bf16_lo (W_in[(k - 6) * HID + nn]);  // hi*Wlo
        }
        wp[e] = bits;
    } else if (e < W_USHORTS) {
        int e3 = e - MID_ELEMS - IN_ELEMS;
        int s = e3 / 512, r = e3 % 512, l = r / 8, j = r % 8;
        int c  = s * 4 + (l >> 4);
        int nn = l & 15;
        wp[e] = (nn < 3) ? pack_slot(W_out, 3, c, j, nn) : (unsigned short)0;
    } else if (e < PACK_THREADS) {
        int b = e - W_USHORTS;
        float v = 0.0f;
        if (b < 64)                 { if (b < HID) v = b_in[b]; }
        else if (b < 64 + NMID*64)  { int L = (b - 64) / 64, cc = (b - 64) % 64;
                                      if (cc < HID) v = b_mid[L * HID + cc]; }
        else                        { int cc = b - 64 - NMID * 64;
                                      if (cc < 3) v = b_out[cc]; }
        bp[b] = v;
    }
}

__global__ __launch_bounds__(256) void softmesh_mfma(
    const float* __restrict__ x, const float* __restrict__ y,
    const float* __restrict__ z,
    const unsigned short* __restrict__ wp, const float* __restrict__ bp,
    float* __restrict__ out, int n)
{
    __shared__ unsigned short hsm[4 * 16 * LROWU];   // 19456 B
    const int tid  = threadIdx.x;
    const int wave = tid >> 6, lane = tid & 63;
    const int m = lane & 15, quad = lane >> 4;
    unsigned short* __restrict__ hb = hsm + wave * 16 * LROWU;

    const int i0 = (blockIdx.x * 4 + wave) * 16;
    if (i0 >= n) return;
    int idx = i0 + m; if (idx >= n) idx = n - 1;

    const short8* __restrict__ Wm = (const short8*)wp;                          // [L][t][s][64]
    const short8* __restrict__ Wi = (const short8*)(wp + MID_ELEMS);            // [t][64]
    const short8* __restrict__ Wo = (const short8*)(wp + MID_ELEMS + IN_ELEMS); // [s][64]
    const float* __restrict__ bin  = bp;
    const float* __restrict__ bmid = bp + 64;
    const float* __restrict__ bout = bp + 64 + NMID * 64;

    // A-read base (row m) + per-s ushort offsets; write base per r (dword units)
    const unsigned short* __restrict__ Arow = hb + m * LROWU;
    int aoff[7];
#pragma unroll
    for (int s = 0; s < 7; ++s) {
        int c = s * 4 + quad;
        aoff[s] = (c < 13) ? c * 8 : ((c < 26) ? (c - 13) * 8 : 0);
    }
    unsigned int* __restrict__ wr0 = (unsigned int*)hb + (quad * 4) * (LROWU / 2) + m;

    // ---- input layer (K=32, A in registers) ----
    float xv = x[idx], yv = y[idx], zv = z[idx];
    unsigned short xh = bf16_rne(xv), yh = bf16_rne(yv), zh = bf16_rne(zv);
    unsigned short xl = bf16_lo(xv),  yl = bf16_lo(yv),  zl = bf16_lo(zv);
    short8 af = (short8){0, 0, 0, 0, 0, 0, 0, 0};
    if (quad == 0) {
        af[0] = (short)xh; af[1] = (short)yh; af[2] = (short)zh;
        af[3] = (short)xl; af[4] = (short)yl; af[5] = (short)zl;
        af[6] = (short)xh; af[7] = (short)yh;
    } else if (quad == 1) {
        af[0] = (short)zh;
    }

    f32x4 acc[4];
#pragma unroll
    for (int t = 0; t < 4; ++t) {
        float bv = bin[t * 16 + m];
        f32x4 c4 = (f32x4){bv, bv, bv, bv};
        acc[t] = __builtin_amdgcn_mfma_f32_16x16x32_bf16(af, Wi[t * 64 + lane], c4, 0, 0, 0);
    }
#pragma unroll
    for (int r = 0; r < 4; ++r) {
        unsigned int* wr = wr0 + r * (LROWU / 2);
#pragma unroll
        for (int t = 0; t < 4; ++t) wr[t * 16] = tanh_split_pack(acc[t][r]);
    }

    // ---- 7 mid layers: C[16x64] = A[16x224] * W'[224x64] ----
#pragma unroll 1
    for (int L = 0; L < NMID; ++L) {
        short8 a[7];
#pragma unroll
        for (int s = 0; s < 7; ++s)
            a[s] = *(const short8*)(Arow + aoff[s]);
        const short8* __restrict__ WL = Wm + (L * 28) * 64;
#pragma unroll
        for (int t = 0; t < 4; ++t) {
            float bv = bmid[L * 64 + t * 16 + m];
            f32x4 c4 = (f32x4){bv, bv, bv, bv};
#pragma unroll
            for (int s = 0; s < 7; ++s)
                c4 = __builtin_amdgcn_mfma_f32_16x16x32_bf16(a[s], WL[(t * 7 + s) * 64 + lane], c4, 0, 0, 0);
            acc[t] = c4;
        }
#pragma unroll
        for (int r = 0; r < 4; ++r) {
            unsigned int* wr = wr0 + r * (LROWU / 2);
#pragma unroll
            for (int t = 0; t < 4; ++t) wr[t * 16] = tanh_split_pack(acc[t][r]);
        }
    }

    // ---- output layer: 1 N-tile, cols 0..2 ----
    {
        short8 a[7];
#pragma unroll
        for (int s = 0; s < 7; ++s)
            a[s] = *(const short8*)(Arow + aoff[s]);
        float bv = bout[m];
        f32x4 c4 = (f32x4){bv, bv, bv, bv};
#pragma unroll
        for (int s = 0; s < 7; ++s)
            c4 = __builtin_amdgcn_mfma_f32_16x16x32_bf16(a[s], Wo[s * 64 + lane], c4, 0, 0, 0);
        if (m < 3) {
            int row0 = i0 + quad * 4;
            if (row0 + 3 < n) {
                *(f32x4*)(out + (size_t)m * (size_t)n + row0) = c4;  // 16B coalesced
            } else {
#pragma unroll
                for (int r = 0; r < 4; ++r)
                    if (row0 + r < n) out[(size_t)m * (size_t)n + row0 + r] = c4[r];
            }
        }
    }
}

extern "C" void kernel_launch(void* const* d_in, const int* in_sizes, int n_in,
                              void* d_out, int out_size, void* d_ws, size_t ws_size,
                              hipStream_t stream) {
    const float* x     = (const float*)d_in[0];
    const float* y     = (const float*)d_in[1];
    const float* z     = (const float*)d_in[2];
    const float* W_in  = (const float*)d_in[3];
    const float* b_in  = (const float*)d_in[4];
    const float* W_mid = (const float*)d_in[5];
    const float* b_mid = (const float*)d_in[6];
    const float* W_out = (const float*)d_in[7];
    const float* b_out = (const float*)d_in[8];
    float* out = (float*)d_out;
    int n = in_sizes[0];

    unsigned short* wpp = (unsigned short*)d_ws;
    float* bpf = (float*)((char*)d_ws + W_USHORTS * sizeof(unsigned short));

    int pgrid = (PACK_THREADS + 255) / 256;
    pack_params<<<pgrid, 256, 0, stream>>>(W_in, b_in, W_mid, b_mid, W_out, b_out, wpp, bpf);

    int grid = (n + 63) / 64;   // 4 waves/block, 16 points/wave
    softmesh_mfma<<<grid, 256, 0, stream>>>(x, y, z, wpp, bpf, out, n);
}

// Round 7
// 574.944 us; speedup vs baseline: 1.4603x; 1.4603x over previous
//
#include <hip/hip_runtime.h>

#define HID 50
#define NMID 7
#define NT 4      // N-tiles (64 feats)
#define NS 7      // k-steps (K' = 224)
#define MT 4      // M-tiles per wave (64 points)
#define LROWU 152 // ushorts per h-row: 76 dwords, 304 B, 16B-aligned

// packed weights (ushorts): Mid [L][t][s][64][8]; In [t][64][8]; Out [s][64][8]
#define MID_ELEMS (NMID * NT * NS * 64 * 8)
#define IN_ELEMS  (NT * 64 * 8)
#define OUT_ELEMS (NS * 64 * 8)
#define W_USHORTS (MID_ELEMS + IN_ELEMS + OUT_ELEMS)

using short8 = __attribute__((ext_vector_type(8))) short;
using f32x4  = __attribute__((ext_vector_type(4))) float;

__device__ __forceinline__ unsigned short bf16_rne(float f) {
    unsigned int u = __builtin_bit_cast(unsigned int, f);
    unsigned int r = (u + 0x7FFFu + ((u >> 16) & 1u)) >> 16;
    return (unsigned short)r;
}
__device__ __forceinline__ float bf16_f(unsigned short b) {
    unsigned int u = ((unsigned int)b) << 16;
    return __builtin_bit_cast(float, u);
}
__device__ __forceinline__ unsigned short bf16_lo(float w) {
    return bf16_rne(w - bf16_f(bf16_rne(w)));
}
// tanh -> truncating hi/lo split -> packed dword {lo_bf16 : hi_bf16} via v_perm.
__device__ __forceinline__ unsigned int tanh_split_pack(float a) {
    float e = __builtin_amdgcn_exp2f(a * 2.885390081777927f);
    float r = __builtin_amdgcn_rcpf(e + 1.0f);
    float v = __builtin_fmaf(r, -2.0f, 1.0f);     // tanh = 1 - 2/(e+1)
    unsigned int uv  = __builtin_bit_cast(unsigned int, v);
    unsigned int hif = uv & 0xFFFF0000u;
    float lo = v - __builtin_bit_cast(float, hif);
    unsigned int ul = __builtin_bit_cast(unsigned int, lo);
    return __builtin_amdgcn_perm(ul, uv, 0x07060302u);  // {lo.hi16 : v.hi16}
}

// Chunk map (c = s*4 + quad, 28 chunks of 8 slots):
//  c 0..12 : pass1, A = interleaved (hi,lo) pairs, dwords c*4..  B: both slots W_hi[e]
//  c 13..25: pass2, A = RE-READ of pass1 dwords (c-13)*4..       B: even slot W_lo[e], odd 0
//  c 26    : bias,  A = dword 64 = {1.0,1.0}, dwords 65..67 = 0  B: j0=b_hi, j1=b_lo
//  c 27    : pad,   A = dwords 68..71 = 0                        B: 0
__device__ __forceinline__ unsigned short pack_slot(const float* __restrict__ W, int ld,
                                                    const float* __restrict__ bias,
                                                    int c, int j, int nn) {
    if (c < 13) {
        int e = c * 4 + (j >> 1);
        if (e >= HID) return 0;
        return bf16_rne(W[e * ld + nn]);
    }
    if (c < 26) {
        if (j & 1) return 0;
        int e = (c - 13) * 4 + (j >> 1);
        if (e >= HID) return 0;
        return bf16_lo(W[e * ld + nn]);
    }
    if (c == 26) {
        if (j == 0) return bf16_rne(bias[nn]);
        if (j == 1) return bf16_lo(bias[nn]);
    }
    return 0;
}

__global__ void pack_params(const float* __restrict__ W_in, const float* __restrict__ b_in,
                            const float* __restrict__ W_mid, const float* __restrict__ b_mid,
                            const float* __restrict__ W_out, const float* __restrict__ b_out,
                            unsigned short* __restrict__ wp) {
    int e = blockIdx.x * 256 + threadIdx.x;
    if (e < MID_ELEMS) {
        int L = e / (NT * NS * 512), r1 = e % (NT * NS * 512);
        int t = r1 / (NS * 512),     r2 = r1 % (NS * 512);
        int s = r2 / 512,            r3 = r2 % 512;
        int l = r3 / 8,              j  = r3 % 8;
        int c  = s * 4 + (l >> 4);
        int nn = t * 16 + (l & 15);
        wp[e] = (nn < HID) ? pack_slot(W_mid + L * HID * HID, HID, b_mid + L * HID, c, j, nn)
                           : (unsigned short)0;
    } else if (e < MID_ELEMS + IN_ELEMS) {
        int e2 = e - MID_ELEMS;
        int t = e2 / 512, r = e2 % 512, l = r / 8, j = r % 8;
        int k  = (l >> 4) * 8 + j;
        int nn = t * 16 + (l & 15);
        unsigned short bits = 0;
        if (nn < HID) {
            // pairs A slots [xh,yh,zh, xl,yl,zl, xh,yh | zh, 1.0, 1.0, 0...]
            if (k < 3)        bits = bf16_rne(W_in[k * HID + nn]);        // hi*Whi
            else if (k < 6)   bits = bf16_rne(W_in[(k - 3) * HID + nn]);  // lo*Whi
            else if (k < 9)   bits = bf16_lo (W_in[(k - 6) * HID + nn]);  // hi*Wlo
            else if (k == 9)  bits = bf16_rne(b_in[nn]);                  // 1.0*b_hi
            else if (k == 10) bits = bf16_lo (b_in[nn]);                  // 1.0*b_lo
        }
        wp[e] = bits;
    } else if (e < W_USHORTS) {
        int e3 = e - MID_ELEMS - IN_ELEMS;
        int s = e3 / 512, r = e3 % 512, l = r / 8, j = r % 8;
        int c  = s * 4 + (l >> 4);
        int nn = l & 15;
        wp[e] = (nn < 3) ? pack_slot(W_out, 3, b_out, c, j, nn) : (unsigned short)0;
    }
}

__global__ __launch_bounds__(128) void softmesh_mfma(
    const float* __restrict__ x, const float* __restrict__ y,
    const float* __restrict__ z,
    const unsigned short* __restrict__ wp,
    float* __restrict__ out, int n)
{
    __shared__ unsigned short hsm[2 * 64 * LROWU];   // 2 waves x 64 rows = 38912 B
    const int tid  = threadIdx.x;
    const int wave = tid >> 6, lane = tid & 63;
    const int m = lane & 15, quad = lane >> 4;
    unsigned short* __restrict__ hb = hsm + wave * 64 * LROWU;
    unsigned int* __restrict__ hbd = (unsigned int*)hb;

    const int i0 = (blockIdx.x * 2 + wave) * 64;     // 64 points per wave
    if (i0 >= n) return;

    // one-time init: bias/pad dwords 64..71 of this wave's 64 rows (lane -> row lane)
    {
        unsigned int* p = hbd + lane * 76;
        p[64] = 0x3F803F80u;                          // slots 208,209 = 1.0,1.0 (bias A)
        p[65] = 0u; p[66] = 0u; p[67] = 0u;
        p[68] = 0u; p[69] = 0u; p[70] = 0u; p[71] = 0u;
    }

    // A-read pointers: row m, chunk offset per (s,quad); per-M-tile adds imm mt*4864 B
    const unsigned short* aaddr[NS];
#pragma unroll
    for (int s = 0; s < NS; ++s) {
        int c = s * 4 + quad;
        int dwo = (c < 13) ? c * 4 : ((c < 26) ? (c - 13) * 4 : ((c == 26) ? 64 : 68));
        aaddr[s] = hb + m * LROWU + dwo * 2;
    }
    // epilogue write base: dword (quad*4)*76 + m; imm = ((mt*16+r)*76 + t*16)*4 < 64KB
    unsigned int* __restrict__ wb = hbd + quad * 304 + m;

    const short8* __restrict__ Wm = (const short8*)wp;                          // [L][t][s][64]
    const short8* __restrict__ Wi = (const short8*)(wp + MID_ELEMS);            // [t][64]
    const short8* __restrict__ Wo = (const short8*)(wp + MID_ELEMS + IN_ELEMS); // [s][64]

    // ---- input layer: K=32, A in registers, bias in k=9,10 ----
    short8 Bi[NT];
#pragma unroll
    for (int t = 0; t < NT; ++t) Bi[t] = Wi[t * 64 + lane];

#pragma unroll
    for (int mt = 0; mt < MT; ++mt) {
        int idx = i0 + mt * 16 + m; if (idx >= n) idx = n - 1;
        float xv = x[idx], yv = y[idx], zv = z[idx];
        unsigned short xh = bf16_rne(xv), yh = bf16_rne(yv), zh = bf16_rne(zv);
        unsigned short xl = bf16_lo(xv),  yl = bf16_lo(yv),  zl = bf16_lo(zv);
        short8 af = (short8){0, 0, 0, 0, 0, 0, 0, 0};
        if (quad == 0) {
            af[0] = (short)xh; af[1] = (short)yh; af[2] = (short)zh;
            af[3] = (short)xl; af[4] = (short)yl; af[5] = (short)zl;
            af[6] = (short)xh; af[7] = (short)yh;
        } else if (quad == 1) {
            af[0] = (short)zh;
            af[1] = (short)0x3F80;   // 1.0 pairs b_hi (k=9)
            af[2] = (short)0x3F80;   // 1.0 pairs b_lo (k=10)
        }
#pragma unroll
        for (int t = 0; t < NT; ++t) {
            f32x4 c4 = (f32x4){0.f, 0.f, 0.f, 0.f};
            c4 = __builtin_amdgcn_mfma_f32_16x16x32_bf16(af, Bi[t], c4, 0, 0, 0);
#pragma unroll
            for (int r = 0; r < 4; ++r) {
                unsigned int p = tanh_split_pack(c4[r]);
                if (t < 3 || m < 4) wb[(mt * 16 + r) * 76 + t * 16] = p;
            }
        }
    }

    // ---- 7 mid layers: B (weights+bias) register-cached, reused by 4 M-tiles ----
#pragma unroll 1
    for (int L = 0; L < NMID; ++L) {
        const short8* __restrict__ WL = Wm + L * (NT * NS) * 64;
        short8 Bf[NT * NS];
#pragma unroll
        for (int i = 0; i < NT * NS; ++i) Bf[i] = WL[i * 64 + lane];
#pragma unroll
        for (int mt = 0; mt < MT; ++mt) {
            short8 a[NS];
#pragma unroll
            for (int s = 0; s < NS; ++s)
                a[s] = *(const short8*)((const char*)aaddr[s] + mt * 4864);
            f32x4 cc[NT];
#pragma unroll
            for (int t = 0; t < NT; ++t) {
                f32x4 c4 = (f32x4){0.f, 0.f, 0.f, 0.f};
#pragma unroll
                for (int s = 0; s < NS; ++s)
                    c4 = __builtin_amdgcn_mfma_f32_16x16x32_bf16(a[s], Bf[t * NS + s], c4, 0, 0, 0);
                cc[t] = c4;
            }
#pragma unroll
            for (int t = 0; t < NT; ++t) {
#pragma unroll
                for (int r = 0; r < 4; ++r) {
                    unsigned int p = tanh_split_pack(cc[t][r]);
                    if (t < 3 || m < 4) wb[(mt * 16 + r) * 76 + t * 16] = p;
                }
            }
        }
    }

    // ---- output layer: 1 N-tile (cols 0..2), bias in c=26 ----
    {
        short8 Bo[NS];
#pragma unroll
        for (int s = 0; s < NS; ++s) Bo[s] = Wo[s * 64 + lane];
#pragma unroll
        for (int mt = 0; mt < MT; ++mt) {
            short8 a[NS];
#pragma unroll
            for (int s = 0; s < NS; ++s)
                a[s] = *(const short8*)((const char*)aaddr[s] + mt * 4864);
            f32x4 c4 = (f32x4){0.f, 0.f, 0.f, 0.f};
#pragma unroll
            for (int s = 0; s < NS; ++s)
                c4 = __builtin_amdgcn_mfma_f32_16x16x32_bf16(a[s], Bo[s], c4, 0, 0, 0);
            if (m < 3) {
                int row0 = i0 + mt * 16 + quad * 4;
                if (row0 + 3 < n) {
                    *(f32x4*)(out + (size_t)m * (size_t)n + row0) = c4;
                } else {
#pragma unroll
                    for (int r = 0; r < 4; ++r)
                        if (row0 + r < n) out[(size_t)m * (size_t)n + row0 + r] = c4[r];
                }
            }
        }
    }
}

extern "C" void kernel_launch(void* const* d_in, const int* in_sizes, int n_in,
                              void* d_out, int out_size, void* d_ws, size_t ws_size,
                              hipStream_t stream) {
    const float* x     = (const float*)d_in[0];
    const float* y     = (const float*)d_in[1];
    const float* z     = (const float*)d_in[2];
    const float* W_in  = (const float*)d_in[3];
    const float* b_in  = (const float*)d_in[4];
    const float* W_mid = (const float*)d_in[5];
    const float* b_mid = (const float*)d_in[6];
    const float* W_out = (const float*)d_in[7];
    const float* b_out = (const float*)d_in[8];
    float* out = (float*)d_out;
    int n = in_sizes[0];

    unsigned short* wpp = (unsigned short*)d_ws;

    int pgrid = (W_USHORTS + 255) / 256;
    pack_params<<<pgrid, 256, 0, stream>>>(W_in, b_in, W_mid, b_mid, W_out, b_out, wpp);

    int grid = (n + 127) / 128;   // 2 waves/block, 64 points/wave
    softmesh_mfma<<<grid, 128, 0, stream>>>(x, y, z, wpp, out, n);
}

// Round 9
// 332.346 us; speedup vs baseline: 2.5262x; 1.7300x over previous
//
#include <hip/hip_runtime.h>

#define HID 50
#define NMID 7
#define NT 4        // N-tiles (64 feature cols)
#define NS 2        // k-chunks per tile (K' = 64)
#define MT 4        // M-tiles per wave (64 points)
#define LROWB 144   // bytes per LDS h-row: 64 f16 = 128 B + 16 B pad (36 dwords)

// packed f16 params: Mid [L][t][s][64 lanes][8]; In [t][64][8]; Out [s][64][8]
#define MID_ELEMS (NMID * NT * NS * 64 * 8)   // 28672
#define IN_ELEMS  (NT * 64 * 8)               // 2048
#define OUT_ELEMS (NS * 64 * 8)               // 1024
#define W_HALFS   (MID_ELEMS + IN_ELEMS + OUT_ELEMS)

typedef _Float16 half8  __attribute__((ext_vector_type(8)));
typedef float    f32x4  __attribute__((ext_vector_type(4)));

__device__ __forceinline__ unsigned short f16hi(float w) {
    _Float16 h = (_Float16)w;                    // RNE
    return __builtin_bit_cast(unsigned short, h);
}
__device__ __forceinline__ unsigned short f16lo(float w) {
    _Float16 h = (_Float16)w;
    _Float16 l = (_Float16)(w - (float)h);
    return __builtin_bit_cast(unsigned short, l);
}
__device__ __forceinline__ float tanh_fast(float a) {
    float e = __builtin_amdgcn_exp2f(a * 2.885390081777927f);
    float r = __builtin_amdgcn_rcpf(e + 1.0f);
    return __builtin_fmaf(r, -2.0f, 1.0f);       // tanh = 1 - 2/(e+1)
}

// k-permutation: storage position k = 4*km + kt holds logical in-feature
// fi = 16*kt + km (valid when kt<3 or km<2); k=11 -> bias_hi; k=15 -> bias_lo;
// kt==3,km>=4 -> zero row. Chosen so the producing lane (m=km) owns dwords
// 2m,2m+1 of each LDS row -> conflict-free ds_write_b64 epilogue, no masking.
__device__ __forceinline__ unsigned short pack_kn(const float* __restrict__ W, int ld,
                                                  const float* __restrict__ bias,
                                                  int k, int fo) {
    int km = k >> 2, kt = k & 3;
    if (kt < 3 || km < 2) { int fi = kt * 16 + km; return (fi < HID) ? f16hi(W[fi * ld + fo]) : (unsigned short)0; }
    if (km == 2) return f16hi(bias[fo]);
    if (km == 3) return f16lo(bias[fo]);
    return 0;
}

__global__ void pack_params(const float* __restrict__ W_in, const float* __restrict__ b_in,
                            const float* __restrict__ W_mid, const float* __restrict__ b_mid,
                            const float* __restrict__ W_out, const float* __restrict__ b_out,
                            unsigned short* __restrict__ wp) {
    int e = blockIdx.x * 256 + threadIdx.x;
    if (e < MID_ELEMS) {
        int L = e / (NT * NS * 512), r1 = e % (NT * NS * 512);
        int t = r1 / (NS * 512),     r2 = r1 % (NS * 512);
        int s = r2 / 512,            r3 = r2 % 512;
        int l = r3 / 8,              j  = r3 % 8;
        int k  = s * 32 + ((l >> 4) << 3) + j;
        int fo = t * 16 + (l & 15);
        wp[e] = (fo < HID) ? pack_kn(W_mid + L * HID * HID, HID, b_mid + L * HID, k, fo)
                           : (unsigned short)0;
    } else if (e < MID_ELEMS + IN_ELEMS) {
        int e2 = e - MID_ELEMS;
        int t = e2 / 512, r = e2 % 512, l = r / 8, j = r % 8;
        int k  = ((l >> 4) << 3) + j;       // only quad 0 (k<8) carries data
        int fo = t * 16 + (l & 15);
        unsigned short bits = 0;
        if (fo < HID) {
            if (k < 3)       bits = f16hi(W_in[k * HID + fo]);        // pairs xh,yh,zh
            else if (k < 6)  bits = f16hi(W_in[(k - 3) * HID + fo]);  // pairs xl,yl,zl (same Whi)
            else if (k == 6) bits = f16hi(b_in[fo]);                  // pairs 1.0
            else if (k == 7) bits = f16lo(b_in[fo]);                  // pairs 1.0
        }
        wp[e] = bits;
    } else if (e < W_HALFS) {
        int e3 = e - MID_ELEMS - IN_ELEMS;
        int s = e3 / 512, r = e3 % 512, l = r / 8, j = r % 8;
        int k  = s * 32 + ((l >> 4) << 3) + j;
        int fo = l & 15;
        wp[e] = (fo < 3) ? pack_kn(W_out, 3, b_out, k, fo) : (unsigned short)0;
    }
}

// epilogue: 4 tanh -> 2 pk-cvt -> 1 ds_write_b64 per (mt,r). Lane (quad,m)
// writes dwords 2m,2m+1 of row quad*4+r (k=4m+0..3). Lanes m=2,3 substitute
// 1.0 for their t=3 slot (bias A-values at k=11,15). All other pad slots are
// tanh(0)=0 (B cols >=50 pack to zero) -- finite, and B rows there are zero.
__device__ __forceinline__ void epilogue_store(const f32x4* cc, unsigned char* wmt, bool bias_lane) {
#pragma unroll
    for (int r = 0; r < 4; ++r) {
        float v0 = tanh_fast(cc[0][r]);
        float v1 = tanh_fast(cc[1][r]);
        float v2 = tanh_fast(cc[2][r]);
        float v3 = tanh_fast(cc[3][r]);
        v3 = bias_lane ? 1.0f : v3;
        auto p0 = __builtin_amdgcn_cvt_pkrtz(v0, v1);   // __fp16 ext_vector(2)
        auto p1 = __builtin_amdgcn_cvt_pkrtz(v2, v3);
        uint2 q;
        q.x = __builtin_bit_cast(unsigned int, p0);
        q.y = __builtin_bit_cast(unsigned int, p1);
        *(uint2*)(wmt + r * LROWB) = q;
    }
}

__global__ __launch_bounds__(128, 4) void softmesh_mfma(
    const float* __restrict__ x, const float* __restrict__ y,
    const float* __restrict__ z,
    const unsigned short* __restrict__ wp,
    float* __restrict__ out, int n)
{
    __shared__ unsigned char hsm[2 * 64 * LROWB];   // 18432 B -> 8 blocks/CU
    const int tid  = threadIdx.x;
    const int wave = tid >> 6, lane = tid & 63;
    const int m = lane & 15, quad = lane >> 4;
    unsigned char* __restrict__ hb = hsm + wave * 64 * LROWB;

    const int i0 = (blockIdx.x * 2 + wave) * 64;
    if (i0 >= n) return;

    const half8* __restrict__ Wm = (const half8*)wp;
    const half8* __restrict__ Wi = Wm + MID_ELEMS / 8;
    const half8* __restrict__ Wo = Wi + IN_ELEMS / 8;

    const unsigned char* __restrict__ arow = hb + m * LROWB + quad * 16;
    unsigned char* __restrict__ wbase = hb + (quad * 4) * LROWB + m * 8;
    const bool bias_lane = (m == 2) || (m == 3);

    // ---- input layer: K=32, A in registers (hi/lo x + bias slots) ----
    {
        half8 Bi[NT];
#pragma unroll
        for (int t = 0; t < NT; ++t) Bi[t] = Wi[t * 64 + lane];
#pragma unroll
        for (int mt = 0; mt < MT; ++mt) {
            int idx = i0 + mt * 16 + m; if (idx >= n) idx = n - 1;
            float xv = x[idx], yv = y[idx], zv = z[idx];
            _Float16 xh = (_Float16)xv, yh = (_Float16)yv, zh = (_Float16)zv;
            _Float16 xl = (_Float16)(xv - (float)xh);
            _Float16 yl = (_Float16)(yv - (float)yh);
            _Float16 zl = (_Float16)(zv - (float)zh);
            half8 af = {0, 0, 0, 0, 0, 0, 0, 0};
            if (quad == 0) {
                af[0] = xh; af[1] = yh; af[2] = zh;
                af[3] = xl; af[4] = yl; af[5] = zl;
                af[6] = (_Float16)1.0f; af[7] = (_Float16)1.0f;  // bias hi/lo
            }
            f32x4 cc[NT];
#pragma unroll
            for (int t = 0; t < NT; ++t) {
                f32x4 c4 = (f32x4){0.f, 0.f, 0.f, 0.f};
                cc[t] = __builtin_amdgcn_mfma_f32_16x16x32_f16(af, Bi[t], c4, 0, 0, 0);
            }
            epilogue_store(cc, wbase + mt * 16 * LROWB, bias_lane);
        }
    }

    // ---- 7 mid layers: C[16x64] = A[16x64] * W'[64x64], B register-cached ----
#pragma unroll 1
    for (int L = 0; L < NMID; ++L) {
        half8 Bf[NT * NS];
#pragma unroll
        for (int i = 0; i < NT * NS; ++i) Bf[i] = Wm[(L * NT * NS + i) * 64 + lane];
#pragma unroll
        for (int mt = 0; mt < MT; ++mt) {
            half8 a0 = *(const half8*)(arow + mt * 16 * LROWB);
            half8 a1 = *(const half8*)(arow + mt * 16 * LROWB + 64);
            f32x4 cc[NT];
#pragma unroll
            for (int t = 0; t < NT; ++t) {
                f32x4 c4 = (f32x4){0.f, 0.f, 0.f, 0.f};
                c4 = __builtin_amdgcn_mfma_f32_16x16x32_f16(a0, Bf[t * NS + 0], c4, 0, 0, 0);
                c4 = __builtin_amdgcn_mfma_f32_16x16x32_f16(a1, Bf[t * NS + 1], c4, 0, 0, 0);
                cc[t] = c4;
            }
            epilogue_store(cc, wbase + mt * 16 * LROWB, bias_lane);
        }
    }

    // ---- output layer: 1 N-tile, cols 0..2 ----
    {
        half8 Bo0 = Wo[lane], Bo1 = Wo[64 + lane];
#pragma unroll
        for (int mt = 0; mt < MT; ++mt) {
            half8 a0 = *(const half8*)(arow + mt * 16 * LROWB);
            half8 a1 = *(const half8*)(arow + mt * 16 * LROWB + 64);
            f32x4 c4 = (f32x4){0.f, 0.f, 0.f, 0.f};
            c4 = __builtin_amdgcn_mfma_f32_16x16x32_f16(a0, Bo0, c4, 0, 0, 0);
            c4 = __builtin_amdgcn_mfma_f32_16x16x32_f16(a1, Bo1, c4, 0, 0, 0);
            if (m < 3) {
                int row0 = i0 + mt * 16 + quad * 4;
                if (row0 + 3 < n) {
                    *(f32x4*)(out + (size_t)m * (size_t)n + row0) = c4;
                } else {
#pragma unroll
                    for (int r = 0; r < 4; ++r)
                        if (row0 + r < n) out[(size_t)m * (size_t)n + row0 + r] = c4[r];
                }
            }
        }
    }
}

extern "C" void kernel_launch(void* const* d_in, const int* in_sizes, int n_in,
                              void* d_out, int out_size, void* d_ws, size_t ws_size,
                              hipStream_t stream) {
    const float* x     = (const float*)d_in[0];
    const float* y     = (const float*)d_in[1];
    const float* z     = (const float*)d_in[2];
    const float* W_in  = (const float*)d_in[3];
    const float* b_in  = (const float*)d_in[4];
    const float* W_mid = (const float*)d_in[5];
    const float* b_mid = (const float*)d_in[6];
    const float* W_out = (const float*)d_in[7];
    const float* b_out = (const float*)d_in[8];
    float* out = (float*)d_out;
    int n = in_sizes[0];

    unsigned short* wpp = (unsigned short*)d_ws;

    int pgrid = (W_HALFS + 255) / 256;
    pack_params<<<pgrid, 256, 0, stream>>>(W_in, b_in, W_mid, b_mid, W_out, b_out, wpp);

    int grid = (n + 127) / 128;   // 2 waves/block, 64 points/wave
    softmesh_mfma<<<grid, 128, 0, stream>>>(x, y, z, wpp, out, n);
}

// Round 11
// 330.415 us; speedup vs baseline: 2.5409x; 1.0058x over previous
//
#include <hip/hip_runtime.h>

#define HID 50
#define NMID 7
#define NT 4        // N-tiles (64 feature cols)
#define NS 2        // k-chunks per tile (K' = 64)
#define MT 4        // M-tiles per wave (64 points)
#define LROWB 128   // bytes per LDS h-row: 64 f16, XOR-swizzled (no pad)

// packed f16 params: Mid [L][t][s][64 lanes][8]; In [t][64][8]; Out [s][64][8]
#define MID_ELEMS (NMID * NT * NS * 64 * 8)   // 28672
#define IN_ELEMS  (NT * 64 * 8)               // 2048
#define OUT_ELEMS (NS * 64 * 8)               // 1024
#define W_HALFS   (MID_ELEMS + IN_ELEMS + OUT_ELEMS)

typedef _Float16 half8  __attribute__((ext_vector_type(8)));
typedef float    f32x4  __attribute__((ext_vector_type(4)));

__device__ __forceinline__ unsigned short f16hi(float w) {
    _Float16 h = (_Float16)w;                    // RNE
    return __builtin_bit_cast(unsigned short, h);
}
__device__ __forceinline__ unsigned short f16lo(float w) {
    _Float16 h = (_Float16)w;
    _Float16 l = (_Float16)(w - (float)h);
    return __builtin_bit_cast(unsigned short, l);
}
__device__ __forceinline__ float tanh_fast(float a) {
    float e = __builtin_amdgcn_exp2f(a * 2.885390081777927f);
    float r = __builtin_amdgcn_rcpf(e + 1.0f);
    return __builtin_fmaf(r, -2.0f, 1.0f);       // tanh = 1 - 2/(e+1)
}

// k-permutation: storage position k = 4*km + kt holds logical in-feature
// fi = 16*kt + km (valid when kt<3 or km<2); k=11 -> bias_hi; k=15 -> bias_lo.
// Producing lane (m=km) owns dwords 2m,2m+1 of each LDS row.
__device__ __forceinline__ unsigned short pack_kn(const float* __restrict__ W, int ld,
                                                  const float* __restrict__ bias,
                                                  int k, int fo) {
    int km = k >> 2, kt = k & 3;
    if (kt < 3 || km < 2) { int fi = kt * 16 + km; return (fi < HID) ? f16hi(W[fi * ld + fo]) : (unsigned short)0; }
    if (km == 2) return f16hi(bias[fo]);
    if (km == 3) return f16lo(bias[fo]);
    return 0;
}

__global__ void pack_params(const float* __restrict__ W_in, const float* __restrict__ b_in,
                            const float* __restrict__ W_mid, const float* __restrict__ b_mid,
                            const float* __restrict__ W_out, const float* __restrict__ b_out,
                            unsigned short* __restrict__ wp) {
    int e = blockIdx.x * 256 + threadIdx.x;
    if (e < MID_ELEMS) {
        int L = e / (NT * NS * 512), r1 = e % (NT * NS * 512);
        int t = r1 / (NS * 512),     r2 = r1 % (NS * 512);
        int s = r2 / 512,            r3 = r2 % 512;
        int l = r3 / 8,              j  = r3 % 8;
        int k  = s * 32 + ((l >> 4) << 3) + j;
        int fo = t * 16 + (l & 15);
        wp[e] = (fo < HID) ? pack_kn(W_mid + L * HID * HID, HID, b_mid + L * HID, k, fo)
                           : (unsigned short)0;
    } else if (e < MID_ELEMS + IN_ELEMS) {
        int e2 = e - MID_ELEMS;
        int t = e2 / 512, r = e2 % 512, l = r / 8, j = r % 8;
        int k  = ((l >> 4) << 3) + j;       // only quad 0 (k<8) carries data
        int fo = t * 16 + (l & 15);
        unsigned short bits = 0;
        if (fo < HID) {
            if (k < 3)       bits = f16hi(W_in[k * HID + fo]);        // pairs xh,yh,zh
            else if (k < 6)  bits = f16hi(W_in[(k - 3) * HID + fo]);  // pairs xl,yl,zl
            else if (k == 6) bits = f16hi(b_in[fo]);                  // pairs 1.0
            else if (k == 7) bits = f16lo(b_in[fo]);                  // pairs 1.0
        }
        wp[e] = bits;
    } else if (e < W_HALFS) {
        int e3 = e - MID_ELEMS - IN_ELEMS;
        int s = e3 / 512, r = e3 % 512, l = r / 8, j = r % 8;
        int k  = s * 32 + ((l >> 4) << 3) + j;
        int fo = l & 15;
        wp[e] = (fo < 3) ? pack_kn(W_out, 3, b_out, k, fo) : (unsigned short)0;
    }
}

// XOR-swizzled LDS: row p (64 f16 = 8 chunks of 16B) stores logical chunk c
// at physical chunk c ^ (p&7). ROUND-10 BUG: the swizzle depends on the FULL
// row index p = quad*4 + r, but epilogue_store got only wr[0] (p=quad*4) and
// added a uniform r*128B stride -> rows r=1..3 landed at the wrong chunk.
// Fix: index the per-r pointer array wr[r]; only the mt offset (16 rows,
// (p+16mt)&7 == p&7) is swizzle-invariant and may be added uniformly.
__device__ __forceinline__ void epilogue_store(const f32x4* cc, uint2* const* wr, int mtoff,
                                               bool bias_lane) {
#pragma unroll
    for (int r = 0; r < 4; ++r) {
        float v0 = tanh_fast(cc[0][r]);
        float v1 = tanh_fast(cc[1][r]);
        float v2 = tanh_fast(cc[2][r]);
        float v3 = tanh_fast(cc[3][r]);
        v3 = bias_lane ? 1.0f : v3;          // k=11/15 bias A-slots (m=2,3)
        auto p0 = __builtin_amdgcn_cvt_pkrtz(v0, v1);
        auto p1 = __builtin_amdgcn_cvt_pkrtz(v2, v3);
        uint2 q;
        q.x = __builtin_bit_cast(unsigned int, p0);
        q.y = __builtin_bit_cast(unsigned int, p1);
        wr[r][mtoff] = q;
    }
}

__global__ __launch_bounds__(128, 5) void softmesh_mfma(
    const float* __restrict__ x, const float* __restrict__ y,
    const float* __restrict__ z,
    const unsigned short* __restrict__ wp,
    float* __restrict__ out, int n)
{
    __shared__ unsigned char hsm[2 * 64 * LROWB];   // 16384 B
    const int tid  = threadIdx.x;
    const int wave = tid >> 6, lane = tid & 63;
    const int m = lane & 15, quad = lane >> 4;
    unsigned char* __restrict__ hb = hsm + wave * 64 * LROWB;

    const int i0 = (blockIdx.x * 2 + wave) * 64;
    if (i0 >= n) return;

    const half8* __restrict__ Wm = (const half8*)wp;
    const half8* __restrict__ Wi = Wm + MID_ELEMS / 8;
    const half8* __restrict__ Wo = Wi + IN_ELEMS / 8;

    // A-read pointers (row m, logical chunks quad and quad+4); +mt*2048 B per tile
    const unsigned char* __restrict__ ar0 = hb + m * LROWB + ((quad ^ (m & 7)) << 4);
    const unsigned char* __restrict__ ar1 = hb + m * LROWB + (((quad + 4) ^ (m & 7)) << 4);
    // write pointers: row p=quad*4+r, physical chunk (m>>1)^(p&7), half (m&1)
    uint2* wr[4];
#pragma unroll
    for (int r = 0; r < 4; ++r) {
        int p = quad * 4 + r;
        wr[r] = (uint2*)(hb + p * LROWB + (((m >> 1) ^ (p & 7)) << 4) + (m & 1) * 8);
    }
    const bool bias_lane = (m == 2) || (m == 3);

    // ---- layer-0 B cache + input-layer B ----
    half8 Bc[NT * NS];
#pragma unroll
    for (int i = 0; i < NT * NS; ++i) Bc[i] = Wm[i * 64 + lane];
    half8 Bi[NT];
#pragma unroll
    for (int t = 0; t < NT; ++t) Bi[t] = Wi[t * 64 + lane];

    // ---- input layer: K=32, A in registers (hi/lo x + bias slots) ----
#pragma unroll
    for (int mt = 0; mt < MT; ++mt) {
        int idx = i0 + mt * 16 + m; if (idx >= n) idx = n - 1;
        float xv = x[idx], yv = y[idx], zv = z[idx];
        _Float16 xh = (_Float16)xv, yh = (_Float16)yv, zh = (_Float16)zv;
        _Float16 xl = (_Float16)(xv - (float)xh);
        _Float16 yl = (_Float16)(yv - (float)yh);
        _Float16 zl = (_Float16)(zv - (float)zh);
        half8 af = {0, 0, 0, 0, 0, 0, 0, 0};
        if (quad == 0) {
            af[0] = xh; af[1] = yh; af[2] = zh;
            af[3] = xl; af[4] = yl; af[5] = zl;
            af[6] = (_Float16)1.0f; af[7] = (_Float16)1.0f;  // bias hi/lo
        }
        f32x4 cc[NT];
#pragma unroll
        for (int t = 0; t < NT; ++t) {
            f32x4 c4 = (f32x4){0.f, 0.f, 0.f, 0.f};
            cc[t] = __builtin_amdgcn_mfma_f32_16x16x32_f16(af, Bi[t], c4, 0, 0, 0);
        }
        epilogue_store(cc, wr, mt * 256, bias_lane);
    }

    // ---- 7 mid layers, fully unrolled; next-layer B prefetched under epilogue ----
#pragma unroll
    for (int L = 0; L < NMID; ++L) {
        half8 Bn[NT * NS];
        if (L < NMID - 1) {
#pragma unroll
            for (int i = 0; i < NT * NS; ++i) Bn[i] = Wm[((L + 1) * NT * NS + i) * 64 + lane];
        } else {
            Bn[0] = Wo[lane]; Bn[1] = Wo[64 + lane];
#pragma unroll
            for (int i = 2; i < NT * NS; ++i) Bn[i] = Bc[i];   // dead
        }
#pragma unroll
        for (int mt = 0; mt < MT; ++mt) {
            half8 a0 = *(const half8*)(ar0 + mt * 2048);
            half8 a1 = *(const half8*)(ar1 + mt * 2048);
            f32x4 cc[NT];
#pragma unroll
            for (int t = 0; t < NT; ++t) {
                f32x4 c4 = (f32x4){0.f, 0.f, 0.f, 0.f};
                c4 = __builtin_amdgcn_mfma_f32_16x16x32_f16(a0, Bc[t * NS + 0], c4, 0, 0, 0);
                c4 = __builtin_amdgcn_mfma_f32_16x16x32_f16(a1, Bc[t * NS + 1], c4, 0, 0, 0);
                cc[t] = c4;
            }
            epilogue_store(cc, wr, mt * 256, bias_lane);
        }
#pragma unroll
        for (int i = 0; i < NT * NS; ++i) Bc[i] = Bn[i];
    }

    // ---- output layer: 1 N-tile, cols 0..2 (B = Bc[0], Bc[1]) ----
#pragma unroll
    for (int mt = 0; mt < MT; ++mt) {
        half8 a0 = *(const half8*)(ar0 + mt * 2048);
        half8 a1 = *(const half8*)(ar1 + mt * 2048);
        f32x4 c4 = (f32x4){0.f, 0.f, 0.f, 0.f};
        c4 = __builtin_amdgcn_mfma_f32_16x16x32_f16(a0, Bc[0], c4, 0, 0, 0);
        c4 = __builtin_amdgcn_mfma_f32_16x16x32_f16(a1, Bc[1], c4, 0, 0, 0);
        if (m < 3) {
            int row0 = i0 + mt * 16 + quad * 4;
            if (row0 + 3 < n) {
                *(f32x4*)(out + (size_t)m * (size_t)n + row0) = c4;
            } else {
#pragma unroll
                for (int r = 0; r < 4; ++r)
                    if (row0 + r < n) out[(size_t)m * (size_t)n + row0 + r] = c4[r];
            }
        }
    }
}

extern "C" void kernel_launch(void* const* d_in, const int* in_sizes, int n_in,
                              void* d_out, int out_size, void* d_ws, size_t ws_size,
                              hipStream_t stream) {
    const float* x     = (const float*)d_in[0];
    const float* y     = (const float*)d_in[1];
    const float* z     = (const float*)d_in[2];
    const float* W_in  = (const float*)d_in[3];
    const float* b_in  = (const float*)d_in[4];
    const float* W_mid = (const float*)d_in[5];
    const float* b_mid = (const float*)d_in[6];
    const float* W_out = (const float*)d_in[7];
    const float* b_out = (const float*)d_in[8];
    float* out = (float*)d_out;
    int n = in_sizes[0];

    unsigned short* wpp = (unsigned short*)d_ws;

    int pgrid = (W_HALFS + 255) / 256;
    pack_params<<<pgrid, 256, 0, stream>>>(W_in, b_in, W_mid, b_mid, W_out, b_out, wpp);

    int grid = (n + 127) / 128;   // 2 waves/block, 64 points/wave
    softmesh_mfma<<<grid, 128, 0, stream>>>(x, y, z, wpp, out, n);
}